// Round 17
// baseline (413.133 us; speedup 1.0000x reference)
//
#include <hip/hip_runtime.h>
#include <math.h>

typedef __attribute__((ext_vector_type(8))) short short8;
typedef __attribute__((ext_vector_type(4))) float f32x4;
typedef __attribute__((ext_vector_type(16))) float f32x16;
typedef __attribute__((ext_vector_type(4))) float f4;
typedef __attribute__((ext_vector_type(4))) unsigned short us4;
typedef __attribute__((ext_vector_type(2))) unsigned int u32x2;

#define MFMA16(a,b,c) __builtin_amdgcn_mfma_f32_16x16x32_bf16(a,b,c,0,0,0)
#define MFMA32(a,b,c) __builtin_amdgcn_mfma_f32_32x32x16_bf16(a,b,c,0,0,0)

__device__ __forceinline__ unsigned short f2bf(float f) {
  unsigned int u = __float_as_uint(f);
  u = (u + 0x7FFFu + ((u >> 16) & 1u)) >> 16;   // RNE
  return (unsigned short)u;
}
__device__ __forceinline__ float bf2f(unsigned short b) {
  return __uint_as_float(((unsigned int)b) << 16);
}
__device__ __forceinline__ unsigned int pk2(float a, float b) {
  unsigned int au = __float_as_uint(a) + 0x8000u;
  unsigned int bu = __float_as_uint(b) + 0x8000u;
  return __builtin_amdgcn_perm(bu, au, 0x07060302u);
}

typedef const __attribute__((address_space(1))) unsigned int* gas_t;
typedef __attribute__((address_space(3))) unsigned int* las_t;
__device__ __forceinline__ void gl16(const void* g, void* l) {
  __builtin_amdgcn_global_load_lds((gas_t)g, (las_t)l, 16, 0, 0);
}

// ---------------- f32 -> bf16 convert (x) ----------------
__global__ void cvt_f32_bf16(const float* __restrict__ in,
                             unsigned short* __restrict__ out, int n4) {
  int i = blockIdx.x * blockDim.x + threadIdx.x;
  const int stride = gridDim.x * blockDim.x;
  for (; i < n4; i += stride) {
    f4 v = ((const f4*)in)[i];
    us4 o;
    o[0] = f2bf(v[0]); o[1] = f2bf(v[1]); o[2] = f2bf(v[2]); o[3] = f2bf(v[3]);
    ((us4*)out)[i] = o;
  }
}

// ---------------- merged weight converts ----------------
__global__ void cvt4_f32_bf16(const float* __restrict__ w0, const float* __restrict__ w1,
                              const float* __restrict__ w2, const float* __restrict__ w3,
                              unsigned short* __restrict__ o0, unsigned short* __restrict__ o1,
                              unsigned short* __restrict__ o2, unsigned short* __restrict__ o3,
                              int n4) {
  const float* in = (blockIdx.y == 0) ? w0 : (blockIdx.y == 1) ? w1 : (blockIdx.y == 2) ? w2 : w3;
  unsigned short* out = (blockIdx.y == 0) ? o0 : (blockIdx.y == 1) ? o1 : (blockIdx.y == 2) ? o2 : o3;
  int i = blockIdx.x * blockDim.x + threadIdx.x;
  const int stride = gridDim.x * blockDim.x;
  for (; i < n4; i += stride) {
    f4 v = ((const f4*)in)[i];
    us4 o;
    o[0] = f2bf(v[0]); o[1] = f2bf(v[1]); o[2] = f2bf(v[2]); o[3] = f2bf(v[3]);
    ((us4*)out)[i] = o;
  }
}

// ---------------- 8-phase 256^2 NT GEMM, pairwise-fused phases (R13-proven) ----------------
// u32 offsets: all buffer offsets < 2^31 (qkv 66MB) -> no 64-bit address mads.
__global__ __launch_bounds__(512, 1)
void gemm8(const unsigned short* __restrict__ A,
           const unsigned short* __restrict__ B,
           const float* __restrict__ bias,
           unsigned short* __restrict__ out)
{
  const int bi = blockIdx.x;
  const int wg = (bi & 7) * 63 + (bi >> 3);      // bijective XCD swizzle (504 = 8*63)
  const int m0 = (wg / 18) * 256, n0 = (wg % 18) * 256;

  const int tid = threadIdx.x;
  const int lane = tid & 63, lg = lane >> 4, lr = lane & 15;
  const int wave = tid >> 6, wr = wave >> 2, wc = wave & 3;

  __shared__ __align__(16) unsigned short SMEM[65536];
  auto Abuf = [&](int b) -> unsigned short* { return SMEM + b * 16384; };
  auto Bbuf = [&](int b) -> unsigned short* { return SMEM + 32768 + b * 16384; };

  f32x4 acc[8][4];
#pragma unroll
  for (int m = 0; m < 8; ++m)
#pragma unroll
    for (int n = 0; n < 4; ++n) acc[m][n] = (f32x4){0.f, 0.f, 0.f, 0.f};

  auto stage = [&](const unsigned short* P, int rowBase, int t, unsigned short* lbase) {
    const unsigned k0 = (unsigned)t * 64u;
#pragma unroll
    for (int i = 0; i < 2; ++i) {
      unsigned s = (unsigned)(i * 512 + tid);
      unsigned row = s >> 3, c = s & 7;
      unsigned cc = c ^ (row & 7);
      gl16(P + ((unsigned)(rowBase) + row) * 1536u + k0 + cc * 8u, (char*)lbase + s * 16);
    }
  };
  auto rdA = [&](int buf, int mr, int k) -> short8 {
    int row = mr + lr;
    int byte = (row * 128 + (k + lg * 8) * 2) ^ ((row & 7) << 4);
    return *(const short8*)((const char*)Abuf(buf) + byte);
  };
  auto rdB = [&](int buf, int nr, int k) -> short8 {
    int row = nr + lr;
    int byte = (row * 128 + (k + lg * 8) * 2) ^ ((row & 7) << 4);
    return *(const short8*)((const char*)Bbuf(buf) + byte);
  };

  stage(A, m0,       0, Abuf(0));
  stage(A, m0 + 128, 0, Abuf(0) + 128 * 64);
  stage(B, n0,       0, Bbuf(0));
  stage(B, n0 + 128, 0, Bbuf(0) + 128 * 64);
  stage(B, n0,       1, Bbuf(1));
  stage(B, n0 + 128, 1, Bbuf(1) + 128 * 64);
  asm volatile("s_waitcnt vmcnt(4)" ::: "memory");
  __builtin_amdgcn_s_barrier();

  for (int T = 0; T < 24; ++T) {
    const int cur = T & 1;
    const int tA = (T + 1 < 24) ? T + 1 : 23;
    const int tB = (T + 2 < 24) ? T + 2 : 23;
    short8 bfr[4][2];

    // ---- phase A: stage A(T+1); compute rows 0..63 of wave strip ----
    stage(A, m0,       tA, Abuf(cur ^ 1));
    stage(A, m0 + 128, tA, Abuf(cur ^ 1) + 128 * 64);
#pragma unroll
    for (int n = 0; n < 4; ++n) {
      bfr[n][0] = rdB(cur, wc * 64 + n * 16, 0);
      bfr[n][1] = rdB(cur, wc * 64 + n * 16, 32);
    }
    {
      short8 afr[4][2];
#pragma unroll
      for (int m2 = 0; m2 < 4; ++m2) {
        afr[m2][0] = rdA(cur, wr * 128 + m2 * 16, 0);
        afr[m2][1] = rdA(cur, wr * 128 + m2 * 16, 32);
      }
      __builtin_amdgcn_s_barrier();
      __builtin_amdgcn_s_setprio(1);
#pragma unroll
      for (int m2 = 0; m2 < 4; ++m2)
#pragma unroll
        for (int n = 0; n < 4; ++n) {
          acc[m2][n] = MFMA16(afr[m2][0], bfr[n][0], acc[m2][n]);
          acc[m2][n] = MFMA16(afr[m2][1], bfr[n][1], acc[m2][n]);
        }
      __builtin_amdgcn_s_setprio(0);
      __builtin_amdgcn_s_barrier();
    }

    // ---- phase B: stage B(T+2); compute rows 64..127 ----
    stage(B, n0,       tB, Bbuf(cur));
    stage(B, n0 + 128, tB, Bbuf(cur) + 128 * 64);
    {
      short8 afr[4][2];
#pragma unroll
      for (int m2 = 0; m2 < 4; ++m2) {
        afr[m2][0] = rdA(cur, wr * 128 + 64 + m2 * 16, 0);
        afr[m2][1] = rdA(cur, wr * 128 + 64 + m2 * 16, 32);
      }
      asm volatile("s_waitcnt vmcnt(4)" ::: "memory");  // A(T+1),B(T+1) landed
      __builtin_amdgcn_s_barrier();
      __builtin_amdgcn_s_setprio(1);
#pragma unroll
      for (int m2 = 0; m2 < 4; ++m2)
#pragma unroll
        for (int n = 0; n < 4; ++n) {
          acc[4 + m2][n] = MFMA16(afr[m2][0], bfr[n][0], acc[4 + m2][n]);
          acc[4 + m2][n] = MFMA16(afr[m2][1], bfr[n][1], acc[4 + m2][n]);
        }
      __builtin_amdgcn_s_setprio(0);
      __builtin_amdgcn_s_barrier();
    }
  }
  asm volatile("s_waitcnt vmcnt(0)" ::: "memory");
  __builtin_amdgcn_s_barrier();

  // ---- epilogue: acc -> LDS bf16 (swizzled) -> coalesced global stores ----
#pragma unroll
  for (int n = 0; n < 4; ++n) {
    const int col = wc * 64 + n * 16 + lr;
    const float bs = bias[n0 + col];
#pragma unroll
    for (int m = 0; m < 8; ++m) {
      const int rowb = wr * 128 + m * 16 + lg * 4;
#pragma unroll
      for (int r = 0; r < 4; ++r) {
        int row = rowb + r;
        int byte = row * 512 + ((col * 2) ^ ((row & 7) << 4));
        *(unsigned short*)((char*)SMEM + byte) = f2bf(acc[m][n][r] + bs);
      }
    }
  }
  __builtin_amdgcn_s_barrier();
#pragma unroll
  for (int it = 0; it < 16; ++it) {
    unsigned s = (unsigned)(it * 512 + tid);
    unsigned row = s >> 5, c16 = s & 31;
    unsigned byte = row * 512 + ((c16 * 16) ^ ((row & 7) << 4));
    short8 v = *(const short8*)((const char*)SMEM + byte);
    unsigned grow = (unsigned)m0 + row;
    if (grow < 7040u)
      *(short8*)(out + grow * 4608u + (unsigned)n0 + c16 * 8u) = v;
  }
}

// ---------------- 128^2 NT GEMM (gemm1) ----------------
__global__ __launch_bounds__(256)
void gemm_bt(const unsigned short* __restrict__ A,
             const unsigned short* __restrict__ B,
             const float* __restrict__ bias,
             float* __restrict__ of32,
             int K, int ldo, int nbx, int q, int r)
{
  const int lin = blockIdx.x;
  const int xcd = lin & 7, local = lin >> 3;
  const int wg = (xcd < r) ? (xcd * (q + 1) + local) : (r * (q + 1) + (xcd - r) * q + local);
  const int m0 = (wg / nbx) * 128, n0 = (wg % nbx) * 128;

  const int tid = threadIdx.x;
  const int wave = tid >> 6, lane = tid & 63, lg = lane >> 4, lr = lane & 15;
  const int wr = wave >> 1, wc = wave & 1;

  __shared__ __align__(16) unsigned short Al[128 * 32];
  __shared__ __align__(16) unsigned short Bl[128 * 32];

  f32x4 acc[4][4];
#pragma unroll
  for (int m = 0; m < 4; ++m)
#pragma unroll
    for (int n = 0; n < 4; ++n) acc[m][n] = (f32x4){0.f, 0.f, 0.f, 0.f};

  const int r0 = tid >> 2, r1 = (tid + 256) >> 2;
  const int c0 = (tid & 3) * 8;
  const unsigned arow0 = (unsigned)(m0 + r0) * (unsigned)K, arow1 = (unsigned)(m0 + r1) * (unsigned)K;
  const unsigned brow0 = (unsigned)(n0 + r0) * (unsigned)K, brow1 = (unsigned)(n0 + r1) * (unsigned)K;

  for (int k0 = 0; k0 < K; k0 += 32) {
    gl16(A + arow0 + k0 + c0, (char*)Al + tid * 16);
    gl16(A + arow1 + k0 + c0, (char*)Al + (tid + 256) * 16);
    gl16(B + brow0 + k0 + c0, (char*)Bl + tid * 16);
    gl16(B + brow1 + k0 + c0, (char*)Bl + (tid + 256) * 16);
    __syncthreads();
    short8 af[4], bf[4];
#pragma unroll
    for (int m = 0; m < 4; ++m)
      af[m] = *(const short8*)(Al + (wr * 64 + m * 16 + lr) * 32 + lg * 8);
#pragma unroll
    for (int n = 0; n < 4; ++n)
      bf[n] = *(const short8*)(Bl + (wc * 64 + n * 16 + lr) * 32 + lg * 8);
#pragma unroll
    for (int m = 0; m < 4; ++m)
#pragma unroll
      for (int n = 0; n < 4; ++n)
        acc[m][n] = MFMA16(af[m], bf[n], acc[m][n]);
    __syncthreads();
  }

#pragma unroll
  for (int n = 0; n < 4; ++n) {
    const int col = n0 + wc * 64 + n * 16 + lr;
    const float bs = bias[col];
#pragma unroll
    for (int m = 0; m < 4; ++m) {
      const int row = m0 + wr * 64 + m * 16 + lg * 4;
#pragma unroll
      for (int r2 = 0; r2 < 4; ++r2)
        of32[(unsigned)(row + r2) * (unsigned)ldo + (unsigned)col] = acc[m][n][r2] + bs;
    }
  }
}

// ---------------- fused RMSNorm + RoPE, Q and K in one block ----------------
__global__ __launch_bounds__(256)
void normrope2(unsigned short* __restrict__ qkv, const float* __restrict__ gq,
               const float* __restrict__ gk,
               const float* __restrict__ fc, const float* __restrict__ fs,
               float qsc)
{
  const int l = blockIdx.x, tid = threadIdx.x;
  __shared__ float rowq[1536], rowk[1536];
  __shared__ float sredq[4], sredk[4];
  unsigned short* rpq = qkv + (unsigned)l * 4608u;
  unsigned short* rpk = rpq + 1536;

  float ssq = 0.f, ssk = 0.f;
  if (tid < 192) {
    short8 vq = *(const short8*)(rpq + tid * 8);
    short8 vk = *(const short8*)(rpk + tid * 8);
#pragma unroll
    for (int e = 0; e < 8; ++e) {
      float fq = bf2f((unsigned short)vq[e]);
      float fk = bf2f((unsigned short)vk[e]);
      rowq[tid * 8 + e] = fq; ssq += fq * fq;
      rowk[tid * 8 + e] = fk; ssk += fk * fk;
    }
  }
#pragma unroll
  for (int m = 32; m; m >>= 1) {
    ssq += __shfl_xor(ssq, m, 64);
    ssk += __shfl_xor(ssk, m, 64);
  }
  if ((tid & 63) == 0) { sredq[tid >> 6] = ssq; sredk[tid >> 6] = ssk; }
  __syncthreads();
  const float rsq = rsqrtf((sredq[0] + sredq[1] + sredq[2] + sredq[3]) * (1.f / 1536.f) + 1e-6f);
  const float rsk = rsqrtf((sredk[0] + sredk[1] + sredk[2] + sredk[3]) * (1.f / 1536.f) + 1e-6f);

  const int f_ = l / 880, rem = l % 880, h_ = rem / 40, w_ = rem % 40;
#pragma unroll
  for (int j = 0; j < 3; ++j) {
    int p = tid + j * 256;
    int head = p >> 6, c = p & 63;
    int e = head * 128 + 2 * c;
    int tr = (c < 22) ? f_ : ((c < 43) ? h_ : w_);
    float co = fc[tr * 64 + c], si = fs[tr * 64 + c];
    {
      float xr = rowq[e] * rsq * gq[e];
      float xi = rowq[e + 1] * rsq * gq[e + 1];
      float yr = (xr * co - xi * si) * qsc;
      float yi = (xr * si + xi * co) * qsc;
      *(unsigned int*)(rpq + e) = (unsigned int)f2bf(yr) | ((unsigned int)f2bf(yi) << 16);
    }
    {
      float xr = rowk[e] * rsk * gk[e];
      float xi = rowk[e + 1] * rsk * gk[e + 1];
      float yr = xr * co - xi * si;
      float yi = xr * si + xi * co;
      *(unsigned int*)(rpk + e) = (unsigned int)f2bf(yr) | ((unsigned int)f2bf(yi) << 16);
    }
  }
}

// ---------------- attention staging helpers (256 threads, u32 offsets) ----------------
__device__ __forceinline__ void issueK(const unsigned short* __restrict__ qkv,
                                       int h, int t, int kvlen, int woff, int tid,
                                       unsigned short* Kbuf)
{
  const unsigned fixed = 1536u + (unsigned)h * 128u;
#pragma unroll
  for (int i = 0; i < 4; ++i) {
    int s = i * 256 + tid;
    int kvl = s >> 4;
    unsigned dc = (unsigned)((s & 15) ^ (kvl & 7));
    int j = t * 64 + kvl; j = j < kvlen ? j : kvlen - 1;
    unsigned gk = (unsigned)(j + (j >= 880 ? woff : 0));
    gl16(qkv + gk * 4608u + fixed + dc * 8u, (char*)Kbuf + s * 16);
  }
}

__device__ __forceinline__ void loadV(const unsigned short* __restrict__ qkv,
                                      int h, int t, int kvlen, int woff, int tid,
                                      short8 vp[2][2])
{
  const unsigned fixed = 3072u + (unsigned)h * 128u;
#pragma unroll
  for (int i = 0; i < 2; ++i) {
    int task = i * 256 + tid;
    int dc = task & 15, kp = task >> 4;
    int kvl = kp * 2;
    int j0 = t * 64 + kvl, j1 = j0 + 1;
    j0 = j0 < kvlen ? j0 : kvlen - 1;
    j1 = j1 < kvlen ? j1 : kvlen - 1;
    unsigned g0 = (unsigned)(j0 + (j0 >= 880 ? woff : 0));
    unsigned g1 = (unsigned)(j1 + (j1 >= 880 ? woff : 0));
    vp[i][0] = *(const short8*)(qkv + g0 * 4608u + fixed + (unsigned)dc * 8u);
    vp[i][1] = *(const short8*)(qkv + g1 * 4608u + fixed + (unsigned)dc * 8u);
  }
}

__device__ __forceinline__ void writeV(int tid, short8 vp[2][2], unsigned short* Vt)
{
#pragma unroll
  for (int i = 0; i < 2; ++i) {
    int task = i * 256 + tid;
    int dc = task & 15, kp = task >> 4;
    int kvl = kp * 2;
#pragma unroll
    for (int e = 0; e < 8; ++e) {
      int d = dc * 8 + e;
      int byte = d * 128 + kvl * 2;
      byte ^= (((d & 7) ^ ((d >> 3) & 7)) << 4);
      *(unsigned int*)((char*)Vt + byte) =
          (unsigned int)(unsigned short)vp[i][0][e] |
          ((unsigned int)(unsigned short)vp[i][1][e] << 16);
    }
  }
}

// ---------------- chunked sink+window attention (R13-verified: 2 blocks/CU, dbuf V) ----------------
// DO NOT change LDS size / launch_bounds / grid: 3 blocks/CU explodes L2->HBM fetch 7x
// (R6/R7/R8/R14 all measured). 64KB LDS + (256,2) + dim3(14,4,12) is the proven config.
__global__ __launch_bounds__(256, 2)
void attn_kern(const unsigned short* __restrict__ qkv,
               unsigned short* __restrict__ ob)
{
  const int qt = blockIdx.x, ci = blockIdx.y, h = blockIdx.z;
  const int tid = threadIdx.x, wave = tid >> 6, lane = tid & 63;
  const int l31 = lane & 31, hh = lane >> 5;
  const int chunk_start = ci * 1760, chunk_end = chunk_start + 1760;
  const int wstart = (ci == 0) ? 880 : ci * 1760;
  const int woff = wstart - 880;
  const int kvlen = 880 + (chunk_end - wstart);
  const int q0 = chunk_start + qt * 128;

  __shared__ __align__(16) unsigned short Kl[2][64 * 128];
  __shared__ __align__(16) unsigned short Vt[2][128 * 64];

  int qr = q0 + wave * 32 + l31;
  if (qr >= chunk_end) qr = chunk_end - 1;
  const unsigned short* qp = qkv + (unsigned)qr * 4608u + (unsigned)h * 128u;
  short8 qf[8];
#pragma unroll
  for (int st = 0; st < 8; ++st) qf[st] = *(const short8*)(qp + st * 16 + hh * 8);

  f32x16 Oc[4];
#pragma unroll
  for (int i = 0; i < 4; ++i)
#pragma unroll
    for (int j = 0; j < 16; ++j) Oc[i][j] = 0.f;
  float m_run = -1e30f, l_run = 0.f;
  unsigned int w0[8], w1[8];

  auto computeQK = [&](int t, int cur, f32x16* S0, f32x16* S1) {
    f32x16 a0, a1;
#pragma unroll
    for (int j = 0; j < 16; ++j) { a0[j] = 0.f; a1[j] = 0.f; }
    __builtin_amdgcn_s_setprio(1);
#pragma unroll
    for (int st = 0; st < 8; ++st) {
      int off = 32 * st + 16 * hh;
      int b0 = l31 * 256 + (off ^ ((l31 & 7) << 4));
      short8 k0 = *(const short8*)((const char*)&Kl[cur][0] + b0);
      a0 = MFMA32(k0, qf[st], a0);
      int b1 = (32 + l31) * 256 + (off ^ ((l31 & 7) << 4));
      short8 k1 = *(const short8*)((const char*)&Kl[cur][0] + b1);
      a1 = MFMA32(k1, qf[st], a1);
    }
    __builtin_amdgcn_s_setprio(0);
    if (t * 64 + 64 > kvlen) {
#pragma unroll
      for (int r = 0; r < 16; ++r) {
        int kv0 = t * 64 + (r & 3) + 8 * (r >> 2) + 4 * hh;
        if (kv0 >= kvlen)      a0[r] = -1e30f;
        if (kv0 + 32 >= kvlen) a1[r] = -1e30f;
      }
    }
    *S0 = a0; *S1 = a1;
  };

  auto finishTile = [&](f32x16& s0f, f32x16& s1f) {
    float mx[16];
#pragma unroll
    for (int r = 0; r < 16; ++r) mx[r] = fmaxf(s0f[r], s1f[r]);
#pragma unroll
    for (int w = 8; w; w >>= 1)
#pragma unroll
      for (int r = 0; r < w; ++r) mx[r] = fmaxf(mx[r], mx[r + w]);
    float pm = fmaxf(mx[0], __shfl_xor(mx[0], 32, 64));
    const bool defer = __all(pm <= m_run + 8.f);
    const float mn = defer ? m_run : fmaxf(m_run, pm);
#pragma unroll
    for (int r = 0; r < 16; ++r) {
      s0f[r] = __builtin_amdgcn_exp2f(s0f[r] - mn);
      s1f[r] = __builtin_amdgcn_exp2f(s1f[r] - mn);
    }
    float sm[16];
#pragma unroll
    for (int r = 0; r < 16; ++r) sm[r] = s0f[r] + s1f[r];
#pragma unroll
    for (int w = 8; w; w >>= 1)
#pragma unroll
      for (int r = 0; r < w; ++r) sm[r] += sm[r + w];
    float sum = sm[0] + __shfl_xor(sm[0], 32, 64);
    if (defer) {
      l_run += sum;
    } else {
      float al = __builtin_amdgcn_exp2f(m_run - mn);
      l_run = l_run * al + sum;
      m_run = mn;
#pragma unroll
      for (int i = 0; i < 4; ++i)
#pragma unroll
        for (int j = 0; j < 16; ++j) Oc[i][j] *= al;
    }
#pragma unroll
    for (int m = 0; m < 8; ++m) {
      w0[m] = pk2(s0f[2 * m], s0f[2 * m + 1]);
      w1[m] = pk2(s1f[2 * m], s1f[2 * m + 1]);
    }
  };

  auto doPV = [&](int cur) {
    __builtin_amdgcn_s_setprio(1);
#pragma unroll
    for (int s = 0; s < 4; ++s) {
      const unsigned int* w = (s < 2) ? w0 : w1;
      const int lo4 = (s & 1) * 4;
      unsigned int x0 = __shfl_xor(w[lo4 + 2], 32, 64);
      unsigned int x1 = __shfl_xor(w[lo4 + 3], 32, 64);
      unsigned int y0 = __shfl_xor(w[lo4],     32, 64);
      unsigned int y1 = __shfl_xor(w[lo4 + 1], 32, 64);
      unsigned int fw[4];
      fw[0] = hh ? x0 : w[lo4];
      fw[1] = hh ? x1 : w[lo4 + 1];
      fw[2] = hh ? w[lo4 + 2] : y0;
      fw[3] = hh ? w[lo4 + 3] : y1;
      short8 pb = *(const short8*)fw;
#pragma unroll
      for (int dt = 0; dt < 4; ++dt) {
        int d = dt * 32 + l31;
        int byte = d * 128 + s * 32 + hh * 16;
        byte ^= (((d & 7) ^ ((d >> 3) & 7)) << 4);
        short8 vf = *(const short8*)((const char*)&Vt[cur][0] + byte);
        Oc[dt] = MFMA32(vf, pb, Oc[dt]);
      }
    }
    __builtin_amdgcn_s_setprio(0);
  };

  const int nt = (kvlen + 63) >> 6;
  short8 vp[2][2];

  issueK(qkv, h, 0, kvlen, woff, tid, &Kl[0][0]);
  if (nt > 1) issueK(qkv, h, 1, kvlen, woff, tid, &Kl[1][0]);
  loadV(qkv, h, 0, kvlen, woff, tid, vp);
  writeV(tid, vp, &Vt[0][0]);
  __syncthreads();

  f32x16 sp0, sp1;
  computeQK(0, 0, &sp0, &sp1);
  __syncthreads();

  for (int t = 0; t < nt - 1; ++t) {
    const int cur = t & 1;
    if (t + 2 < nt) issueK(qkv, h, t + 2, kvlen, woff, tid, &Kl[cur][0]);
    loadV(qkv, h, t + 1, kvlen, woff, tid, vp);

    f32x16 sc0, sc1;
    computeQK(t + 1, cur ^ 1, &sc0, &sc1);
    finishTile(sp0, sp1);
    writeV(tid, vp, &Vt[cur ^ 1][0]);
    doPV(cur);
    __syncthreads();
    sp0 = sc0; sp1 = sc1;
  }
  finishTile(sp0, sp1);
  doPV((nt - 1) & 1);

  const int qg = q0 + wave * 32 + l31;
  if (qg < chunk_end) {
    const float inv = 1.f / l_run;
    unsigned short* op = ob + (unsigned)qg * 1536u + (unsigned)h * 128u;
#pragma unroll
    for (int dt = 0; dt < 4; ++dt) {
#pragma unroll
      for (int gblk = 0; gblk < 4; ++gblk) {
        int d = dt * 32 + gblk * 8 + hh * 4;
        unsigned int u0 = pk2(Oc[dt][4 * gblk]     * inv, Oc[dt][4 * gblk + 1] * inv);
        unsigned int u1 = pk2(Oc[dt][4 * gblk + 2] * inv, Oc[dt][4 * gblk + 3] * inv);
        u32x2 uu; uu[0] = u0; uu[1] = u1;
        *(u32x2*)(op + d) = uu;
      }
    }
  }
}

// ---------------- launch ----------------
extern "C" void kernel_launch(void* const* d_in, const int* in_sizes, int n_in,
                              void* d_out, int out_size, void* d_ws, size_t ws_size,
                              hipStream_t stream)
{
  const float* x  = (const float*)d_in[0];
  const float* Wq = (const float*)d_in[1];
  const float* bq = (const float*)d_in[2];
  const float* Wk = (const float*)d_in[3];
  const float* bk = (const float*)d_in[4];
  const float* Wv = (const float*)d_in[5];
  const float* bv = (const float*)d_in[6];
  const float* Wo = (const float*)d_in[7];
  const float* bo = (const float*)d_in[8];
  const float* gq = (const float*)d_in[9];
  const float* gk = (const float*)d_in[10];
  const float* fc = (const float*)d_in[11];
  const float* fs = (const float*)d_in[12];

  char* ws = (char*)d_ws;
  unsigned short* xb   = (unsigned short*)(ws);               // 7168x1536 bf16
  unsigned short* obuf = xb;                                  // aliased after gemm0
  unsigned short* wcat = (unsigned short*)(ws + 22020096);
  unsigned short* wob  = (unsigned short*)(ws + 36175872);
  float*          bcat = (float*)(ws + 40894464);
  unsigned short* qkv  = (unsigned short*)(ws + 40912896);

  cvt_f32_bf16<<<2048, 256, 0, stream>>>(x, xb, 10813440 / 4);
  cvt4_f32_bf16<<<dim3(576, 4), 256, 0, stream>>>(
      Wq, Wk, Wv, Wo,
      wcat, wcat + 2359296, wcat + 4718592, wob, 2359296 / 4);
  hipMemcpyAsync(bcat,        bq, 1536 * 4, hipMemcpyDeviceToDevice, stream);
  hipMemcpyAsync(bcat + 1536, bk, 1536 * 4, hipMemcpyDeviceToDevice, stream);
  hipMemcpyAsync(bcat + 3072, bv, 1536 * 4, hipMemcpyDeviceToDevice, stream);

  gemm8<<<504, 512, 0, stream>>>(xb, wcat, bcat, qkv);

  const float qsc = (float)(1.4426950408889634 / sqrt(128.0));
  normrope2<<<7040, 256, 0, stream>>>(qkv, gq, gk, fc, fs, qsc);

  attn_kern<<<dim3(14, 4, 12), 256, 0, stream>>>(qkv, obuf);

  gemm_bt<<<660, 256, 0, stream>>>(obuf, wob, bo, (float*)d_out, 1536, 1536,
                                   12, 660 / 8, 660 % 8);
}

// Round 18
// 393.438 us; speedup vs baseline: 1.0501x; 1.0501x over previous
//
#include <hip/hip_runtime.h>
#include <math.h>

typedef __attribute__((ext_vector_type(8))) short short8;
typedef __attribute__((ext_vector_type(4))) float f32x4;
typedef __attribute__((ext_vector_type(16))) float f32x16;
typedef __attribute__((ext_vector_type(4))) float f4;
typedef __attribute__((ext_vector_type(4))) unsigned short us4;
typedef __attribute__((ext_vector_type(2))) unsigned int u32x2;

#define MFMA16(a,b,c) __builtin_amdgcn_mfma_f32_16x16x32_bf16(a,b,c,0,0,0)
#define MFMA32(a,b,c) __builtin_amdgcn_mfma_f32_32x32x16_bf16(a,b,c,0,0,0)

__device__ __forceinline__ unsigned short f2bf(float f) {
  unsigned int u = __float_as_uint(f);
  u = (u + 0x7FFFu + ((u >> 16) & 1u)) >> 16;   // RNE
  return (unsigned short)u;
}
__device__ __forceinline__ float bf2f(unsigned short b) {
  return __uint_as_float(((unsigned int)b) << 16);
}
__device__ __forceinline__ unsigned int pk2(float a, float b) {
  unsigned int au = __float_as_uint(a) + 0x8000u;
  unsigned int bu = __float_as_uint(b) + 0x8000u;
  return __builtin_amdgcn_perm(bu, au, 0x07060302u);
}

typedef const __attribute__((address_space(1))) unsigned int* gas_t;
typedef __attribute__((address_space(3))) unsigned int* las_t;
__device__ __forceinline__ void gl16(const void* g, void* l) {
  __builtin_amdgcn_global_load_lds((gas_t)g, (las_t)l, 16, 0, 0);
}

// ---------------- f32 -> bf16 convert (x) ----------------
__global__ void cvt_f32_bf16(const float* __restrict__ in,
                             unsigned short* __restrict__ out, int n4) {
  int i = blockIdx.x * blockDim.x + threadIdx.x;
  const int stride = gridDim.x * blockDim.x;
  for (; i < n4; i += stride) {
    f4 v = ((const f4*)in)[i];
    us4 o;
    o[0] = f2bf(v[0]); o[1] = f2bf(v[1]); o[2] = f2bf(v[2]); o[3] = f2bf(v[3]);
    ((us4*)out)[i] = o;
  }
}

// ---------------- merged weight converts ----------------
__global__ void cvt4_f32_bf16(const float* __restrict__ w0, const float* __restrict__ w1,
                              const float* __restrict__ w2, const float* __restrict__ w3,
                              unsigned short* __restrict__ o0, unsigned short* __restrict__ o1,
                              unsigned short* __restrict__ o2, unsigned short* __restrict__ o3,
                              int n4) {
  const float* in = (blockIdx.y == 0) ? w0 : (blockIdx.y == 1) ? w1 : (blockIdx.y == 2) ? w2 : w3;
  unsigned short* out = (blockIdx.y == 0) ? o0 : (blockIdx.y == 1) ? o1 : (blockIdx.y == 2) ? o2 : o3;
  int i = blockIdx.x * blockDim.x + threadIdx.x;
  const int stride = gridDim.x * blockDim.x;
  for (; i < n4; i += stride) {
    f4 v = ((const f4*)in)[i];
    us4 o;
    o[0] = f2bf(v[0]); o[1] = f2bf(v[1]); o[2] = f2bf(v[2]); o[3] = f2bf(v[3]);
    ((us4*)out)[i] = o;
  }
}

// ---------------- 8-phase 256^2 NT GEMM, pairwise-fused phases (R13-proven) ----------------
__global__ __launch_bounds__(512, 1)
void gemm8(const unsigned short* __restrict__ A,
           const unsigned short* __restrict__ B,
           const float* __restrict__ bias,
           unsigned short* __restrict__ out)
{
  const int bi = blockIdx.x;
  const int wg = (bi & 7) * 63 + (bi >> 3);      // bijective XCD swizzle (504 = 8*63)
  const int m0 = (wg / 18) * 256, n0 = (wg % 18) * 256;

  const int tid = threadIdx.x;
  const int lane = tid & 63, lg = lane >> 4, lr = lane & 15;
  const int wave = tid >> 6, wr = wave >> 2, wc = wave & 3;

  __shared__ __align__(16) unsigned short SMEM[65536];
  auto Abuf = [&](int b) -> unsigned short* { return SMEM + b * 16384; };
  auto Bbuf = [&](int b) -> unsigned short* { return SMEM + 32768 + b * 16384; };

  f32x4 acc[8][4];
#pragma unroll
  for (int m = 0; m < 8; ++m)
#pragma unroll
    for (int n = 0; n < 4; ++n) acc[m][n] = (f32x4){0.f, 0.f, 0.f, 0.f};

  auto stage = [&](const unsigned short* P, int rowBase, int t, unsigned short* lbase) {
    const int k0 = t * 64;
#pragma unroll
    for (int i = 0; i < 2; ++i) {
      int s = i * 512 + tid;
      int row = s >> 3, c = s & 7;
      int cc = c ^ (row & 7);
      gl16(P + (long)(rowBase + row) * 1536 + k0 + cc * 8, (char*)lbase + s * 16);
    }
  };
  auto rdA = [&](int buf, int mr, int k) -> short8 {
    int row = mr + lr;
    int byte = (row * 128 + (k + lg * 8) * 2) ^ ((row & 7) << 4);
    return *(const short8*)((const char*)Abuf(buf) + byte);
  };
  auto rdB = [&](int buf, int nr, int k) -> short8 {
    int row = nr + lr;
    int byte = (row * 128 + (k + lg * 8) * 2) ^ ((row & 7) << 4);
    return *(const short8*)((const char*)Bbuf(buf) + byte);
  };

  stage(A, m0,       0, Abuf(0));
  stage(A, m0 + 128, 0, Abuf(0) + 128 * 64);
  stage(B, n0,       0, Bbuf(0));
  stage(B, n0 + 128, 0, Bbuf(0) + 128 * 64);
  stage(B, n0,       1, Bbuf(1));
  stage(B, n0 + 128, 1, Bbuf(1) + 128 * 64);
  asm volatile("s_waitcnt vmcnt(4)" ::: "memory");
  __builtin_amdgcn_s_barrier();

  for (int T = 0; T < 24; ++T) {
    const int cur = T & 1;
    const int tA = (T + 1 < 24) ? T + 1 : 23;
    const int tB = (T + 2 < 24) ? T + 2 : 23;
    short8 bfr[4][2];

    // ---- phase A: stage A(T+1); compute rows 0..63 of wave strip ----
    stage(A, m0,       tA, Abuf(cur ^ 1));
    stage(A, m0 + 128, tA, Abuf(cur ^ 1) + 128 * 64);
#pragma unroll
    for (int n = 0; n < 4; ++n) {
      bfr[n][0] = rdB(cur, wc * 64 + n * 16, 0);
      bfr[n][1] = rdB(cur, wc * 64 + n * 16, 32);
    }
    {
      short8 afr[4][2];
#pragma unroll
      for (int m2 = 0; m2 < 4; ++m2) {
        afr[m2][0] = rdA(cur, wr * 128 + m2 * 16, 0);
        afr[m2][1] = rdA(cur, wr * 128 + m2 * 16, 32);
      }
      __builtin_amdgcn_s_barrier();
      __builtin_amdgcn_s_setprio(1);
#pragma unroll
      for (int m2 = 0; m2 < 4; ++m2)
#pragma unroll
        for (int n = 0; n < 4; ++n) {
          acc[m2][n] = MFMA16(afr[m2][0], bfr[n][0], acc[m2][n]);
          acc[m2][n] = MFMA16(afr[m2][1], bfr[n][1], acc[m2][n]);
        }
      __builtin_amdgcn_s_setprio(0);
      __builtin_amdgcn_s_barrier();
    }

    // ---- phase B: stage B(T+2); compute rows 64..127 ----
    stage(B, n0,       tB, Bbuf(cur));
    stage(B, n0 + 128, tB, Bbuf(cur) + 128 * 64);
    {
      short8 afr[4][2];
#pragma unroll
      for (int m2 = 0; m2 < 4; ++m2) {
        afr[m2][0] = rdA(cur, wr * 128 + 64 + m2 * 16, 0);
        afr[m2][1] = rdA(cur, wr * 128 + 64 + m2 * 16, 32);
      }
      asm volatile("s_waitcnt vmcnt(4)" ::: "memory");  // A(T+1),B(T+1) landed
      __builtin_amdgcn_s_barrier();
      __builtin_amdgcn_s_setprio(1);
#pragma unroll
      for (int m2 = 0; m2 < 4; ++m2)
#pragma unroll
        for (int n = 0; n < 4; ++n) {
          acc[4 + m2][n] = MFMA16(afr[m2][0], bfr[n][0], acc[4 + m2][n]);
          acc[4 + m2][n] = MFMA16(afr[m2][1], bfr[n][1], acc[4 + m2][n]);
        }
      __builtin_amdgcn_s_setprio(0);
      __builtin_amdgcn_s_barrier();
    }
  }
  asm volatile("s_waitcnt vmcnt(0)" ::: "memory");
  __builtin_amdgcn_s_barrier();

  // ---- epilogue: acc -> LDS bf16 (swizzled) -> coalesced global stores ----
#pragma unroll
  for (int n = 0; n < 4; ++n) {
    const int col = wc * 64 + n * 16 + lr;
    const float bs = bias[n0 + col];
#pragma unroll
    for (int m = 0; m < 8; ++m) {
      const int rowb = wr * 128 + m * 16 + lg * 4;
#pragma unroll
      for (int r = 0; r < 4; ++r) {
        int row = rowb + r;
        int byte = row * 512 + ((col * 2) ^ ((row & 7) << 4));
        *(unsigned short*)((char*)SMEM + byte) = f2bf(acc[m][n][r] + bs);
      }
    }
  }
  __builtin_amdgcn_s_barrier();
#pragma unroll
  for (int it = 0; it < 16; ++it) {
    int s = it * 512 + tid;
    int row = s >> 5, c16 = s & 31;
    int byte = row * 512 + ((c16 * 16) ^ ((row & 7) << 4));
    short8 v = *(const short8*)((const char*)SMEM + byte);
    int grow = m0 + row;
    if (grow < 7040)
      *(short8*)(out + (long)grow * 4608 + n0 + c16 * 8) = v;
  }
}

// ---------------- 128^2 NT GEMM (gemm1) ----------------
__global__ __launch_bounds__(256)
void gemm_bt(const unsigned short* __restrict__ A,
             const unsigned short* __restrict__ B,
             const float* __restrict__ bias,
             float* __restrict__ of32,
             int K, int ldo, int nbx, int q, int r)
{
  const int lin = blockIdx.x;
  const int xcd = lin & 7, local = lin >> 3;
  const int wg = (xcd < r) ? (xcd * (q + 1) + local) : (r * (q + 1) + (xcd - r) * q + local);
  const int m0 = (wg / nbx) * 128, n0 = (wg % nbx) * 128;

  const int tid = threadIdx.x;
  const int wave = tid >> 6, lane = tid & 63, lg = lane >> 4, lr = lane & 15;
  const int wr = wave >> 1, wc = wave & 1;

  __shared__ __align__(16) unsigned short Al[128 * 32];
  __shared__ __align__(16) unsigned short Bl[128 * 32];

  f32x4 acc[4][4];
#pragma unroll
  for (int m = 0; m < 4; ++m)
#pragma unroll
    for (int n = 0; n < 4; ++n) acc[m][n] = (f32x4){0.f, 0.f, 0.f, 0.f};

  const int r0 = tid >> 2, r1 = (tid + 256) >> 2;
  const int c0 = (tid & 3) * 8;
  const long arow0 = (long)(m0 + r0) * K, arow1 = (long)(m0 + r1) * K;
  const long brow0 = (long)(n0 + r0) * K, brow1 = (long)(n0 + r1) * K;

  for (int k0 = 0; k0 < K; k0 += 32) {
    gl16(A + arow0 + k0 + c0, (char*)Al + tid * 16);
    gl16(A + arow1 + k0 + c0, (char*)Al + (tid + 256) * 16);
    gl16(B + brow0 + k0 + c0, (char*)Bl + tid * 16);
    gl16(B + brow1 + k0 + c0, (char*)Bl + (tid + 256) * 16);
    __syncthreads();
    short8 af[4], bf[4];
#pragma unroll
    for (int m = 0; m < 4; ++m)
      af[m] = *(const short8*)(Al + (wr * 64 + m * 16 + lr) * 32 + lg * 8);
#pragma unroll
    for (int n = 0; n < 4; ++n)
      bf[n] = *(const short8*)(Bl + (wc * 64 + n * 16 + lr) * 32 + lg * 8);
#pragma unroll
    for (int m = 0; m < 4; ++m)
#pragma unroll
      for (int n = 0; n < 4; ++n)
        acc[m][n] = MFMA16(af[m], bf[n], acc[m][n]);
    __syncthreads();
  }

#pragma unroll
  for (int n = 0; n < 4; ++n) {
    const int col = n0 + wc * 64 + n * 16 + lr;
    const float bs = bias[col];
#pragma unroll
    for (int m = 0; m < 4; ++m) {
      const int row = m0 + wr * 64 + m * 16 + lg * 4;
#pragma unroll
      for (int r2 = 0; r2 < 4; ++r2)
        of32[(long)(row + r2) * ldo + col] = acc[m][n][r2] + bs;
    }
  }
}

// ---------------- fused RMSNorm + RoPE, Q and K in one block ----------------
__global__ __launch_bounds__(256)
void normrope2(unsigned short* __restrict__ qkv, const float* __restrict__ gq,
               const float* __restrict__ gk,
               const float* __restrict__ fc, const float* __restrict__ fs,
               float qsc)
{
  const int l = blockIdx.x, tid = threadIdx.x;
  __shared__ float rowq[1536], rowk[1536];
  __shared__ float sredq[4], sredk[4];
  unsigned short* rpq = qkv + (long)l * 4608;
  unsigned short* rpk = rpq + 1536;

  float ssq = 0.f, ssk = 0.f;
  if (tid < 192) {
    short8 vq = *(const short8*)(rpq + tid * 8);
    short8 vk = *(const short8*)(rpk + tid * 8);
#pragma unroll
    for (int e = 0; e < 8; ++e) {
      float fq = bf2f((unsigned short)vq[e]);
      float fk = bf2f((unsigned short)vk[e]);
      rowq[tid * 8 + e] = fq; ssq += fq * fq;
      rowk[tid * 8 + e] = fk; ssk += fk * fk;
    }
  }
#pragma unroll
  for (int m = 32; m; m >>= 1) {
    ssq += __shfl_xor(ssq, m, 64);
    ssk += __shfl_xor(ssk, m, 64);
  }
  if ((tid & 63) == 0) { sredq[tid >> 6] = ssq; sredk[tid >> 6] = ssk; }
  __syncthreads();
  const float rsq = rsqrtf((sredq[0] + sredq[1] + sredq[2] + sredq[3]) * (1.f / 1536.f) + 1e-6f);
  const float rsk = rsqrtf((sredk[0] + sredk[1] + sredk[2] + sredk[3]) * (1.f / 1536.f) + 1e-6f);

  const int f_ = l / 880, rem = l % 880, h_ = rem / 40, w_ = rem % 40;
#pragma unroll
  for (int j = 0; j < 3; ++j) {
    int p = tid + j * 256;
    int head = p >> 6, c = p & 63;
    int e = head * 128 + 2 * c;
    int tr = (c < 22) ? f_ : ((c < 43) ? h_ : w_);
    float co = fc[tr * 64 + c], si = fs[tr * 64 + c];
    {
      float xr = rowq[e] * rsq * gq[e];
      float xi = rowq[e + 1] * rsq * gq[e + 1];
      float yr = (xr * co - xi * si) * qsc;
      float yi = (xr * si + xi * co) * qsc;
      *(unsigned int*)(rpq + e) = (unsigned int)f2bf(yr) | ((unsigned int)f2bf(yi) << 16);
    }
    {
      float xr = rowk[e] * rsk * gk[e];
      float xi = rowk[e + 1] * rsk * gk[e + 1];
      float yr = xr * co - xi * si;
      float yi = xr * si + xi * co;
      *(unsigned int*)(rpk + e) = (unsigned int)f2bf(yr) | ((unsigned int)f2bf(yi) << 16);
    }
  }
}

// ---------------- attention staging helpers (256 threads) ----------------
__device__ __forceinline__ void issueK(const unsigned short* __restrict__ qkv,
                                       int h, int t, int kvlen, int woff, int tid,
                                       unsigned short* Kbuf)
{
#pragma unroll
  for (int i = 0; i < 4; ++i) {
    int s = i * 256 + tid;
    int kvl = s >> 4;
    int dc = (s & 15) ^ (kvl & 7);
    int j = t * 64 + kvl; j = j < kvlen ? j : kvlen - 1;
    int gk = j + (j >= 880 ? woff : 0);
    gl16(qkv + (long)gk * 4608 + 1536 + h * 128 + dc * 8, (char*)Kbuf + s * 16);
  }
}

__device__ __forceinline__ void loadV(const unsigned short* __restrict__ qkv,
                                      int h, int t, int kvlen, int woff, int tid,
                                      short8 vp[2][2])
{
#pragma unroll
  for (int i = 0; i < 2; ++i) {
    int task = i * 256 + tid;
    int dc = task & 15, kp = task >> 4;
    int kvl = kp * 2;
    int j0 = t * 64 + kvl, j1 = j0 + 1;
    j0 = j0 < kvlen ? j0 : kvlen - 1;
    j1 = j1 < kvlen ? j1 : kvlen - 1;
    int g0 = j0 + (j0 >= 880 ? woff : 0);
    int g1 = j1 + (j1 >= 880 ? woff : 0);
    vp[i][0] = *(const short8*)(qkv + (long)g0 * 4608 + 3072 + h * 128 + dc * 8);
    vp[i][1] = *(const short8*)(qkv + (long)g1 * 4608 + 3072 + h * 128 + dc * 8);
  }
}

__device__ __forceinline__ void writeV(int tid, short8 vp[2][2], unsigned short* Vt)
{
#pragma unroll
  for (int i = 0; i < 2; ++i) {
    int task = i * 256 + tid;
    int dc = task & 15, kp = task >> 4;
    int kvl = kp * 2;
#pragma unroll
    for (int e = 0; e < 8; ++e) {
      int d = dc * 8 + e;
      int byte = d * 128 + kvl * 2;
      byte ^= (((d & 7) ^ ((d >> 3) & 7)) << 4);
      *(unsigned int*)((char*)Vt + byte) =
          (unsigned int)(unsigned short)vp[i][0][e] |
          ((unsigned int)(unsigned short)vp[i][1][e] << 16);
    }
  }
}

// ---------------- chunked sink+window attention (R13-verified: 2 blocks/CU, dbuf V) ----------------
// DO NOT change LDS size / launch_bounds / grid: 3 blocks/CU explodes L2->HBM fetch 7x
// (R6/R7/R8/R14 all measured). 64KB LDS + (256,2) + dim3(14,4,12) is the proven config.
__global__ __launch_bounds__(256, 2)
void attn_kern(const unsigned short* __restrict__ qkv,
               unsigned short* __restrict__ ob)
{
  const int qt = blockIdx.x, ci = blockIdx.y, h = blockIdx.z;
  const int tid = threadIdx.x, wave = tid >> 6, lane = tid & 63;
  const int l31 = lane & 31, hh = lane >> 5;
  const int chunk_start = ci * 1760, chunk_end = chunk_start + 1760;
  const int wstart = (ci == 0) ? 880 : ci * 1760;
  const int woff = wstart - 880;
  const int kvlen = 880 + (chunk_end - wstart);
  const int q0 = chunk_start + qt * 128;

  __shared__ __align__(16) unsigned short Kl[2][64 * 128];
  __shared__ __align__(16) unsigned short Vt[2][128 * 64];

  int qr = q0 + wave * 32 + l31;
  if (qr >= chunk_end) qr = chunk_end - 1;
  const unsigned short* qp = qkv + (long)qr * 4608 + h * 128;
  short8 qf[8];
#pragma unroll
  for (int st = 0; st < 8; ++st) qf[st] = *(const short8*)(qp + st * 16 + hh * 8);

  f32x16 Oc[4];
#pragma unroll
  for (int i = 0; i < 4; ++i)
#pragma unroll
    for (int j = 0; j < 16; ++j) Oc[i][j] = 0.f;
  float m_run = -1e30f, l_run = 0.f;
  unsigned int w0[8], w1[8];

  auto computeQK = [&](int t, int cur, f32x16* S0, f32x16* S1) {
    f32x16 a0, a1;
#pragma unroll
    for (int j = 0; j < 16; ++j) { a0[j] = 0.f; a1[j] = 0.f; }
    __builtin_amdgcn_s_setprio(1);
#pragma unroll
    for (int st = 0; st < 8; ++st) {
      int off = 32 * st + 16 * hh;
      int b0 = l31 * 256 + (off ^ ((l31 & 7) << 4));
      short8 k0 = *(const short8*)((const char*)&Kl[cur][0] + b0);
      a0 = MFMA32(k0, qf[st], a0);
      int b1 = (32 + l31) * 256 + (off ^ ((l31 & 7) << 4));
      short8 k1 = *(const short8*)((const char*)&Kl[cur][0] + b1);
      a1 = MFMA32(k1, qf[st], a1);
    }
    __builtin_amdgcn_s_setprio(0);
    if (t * 64 + 64 > kvlen) {
#pragma unroll
      for (int r = 0; r < 16; ++r) {
        int kv0 = t * 64 + (r & 3) + 8 * (r >> 2) + 4 * hh;
        if (kv0 >= kvlen)      a0[r] = -1e30f;
        if (kv0 + 32 >= kvlen) a1[r] = -1e30f;
      }
    }
    *S0 = a0; *S1 = a1;
  };

  auto finishTile = [&](f32x16& s0f, f32x16& s1f) {
    float mx[16];
#pragma unroll
    for (int r = 0; r < 16; ++r) mx[r] = fmaxf(s0f[r], s1f[r]);
#pragma unroll
    for (int w = 8; w; w >>= 1)
#pragma unroll
      for (int r = 0; r < w; ++r) mx[r] = fmaxf(mx[r], mx[r + w]);
    float pm = fmaxf(mx[0], __shfl_xor(mx[0], 32, 64));
    const bool defer = __all(pm <= m_run + 8.f);
    const float mn = defer ? m_run : fmaxf(m_run, pm);
#pragma unroll
    for (int r = 0; r < 16; ++r) {
      s0f[r] = __builtin_amdgcn_exp2f(s0f[r] - mn);
      s1f[r] = __builtin_amdgcn_exp2f(s1f[r] - mn);
    }
    float sm[16];
#pragma unroll
    for (int r = 0; r < 16; ++r) sm[r] = s0f[r] + s1f[r];
#pragma unroll
    for (int w = 8; w; w >>= 1)
#pragma unroll
      for (int r = 0; r < w; ++r) sm[r] += sm[r + w];
    float sum = sm[0] + __shfl_xor(sm[0], 32, 64);
    if (defer) {
      l_run += sum;
    } else {
      float al = __builtin_amdgcn_exp2f(m_run - mn);
      l_run = l_run * al + sum;
      m_run = mn;
#pragma unroll
      for (int i = 0; i < 4; ++i)
#pragma unroll
        for (int j = 0; j < 16; ++j) Oc[i][j] *= al;
    }
#pragma unroll
    for (int m = 0; m < 8; ++m) {
      w0[m] = pk2(s0f[2 * m], s0f[2 * m + 1]);
      w1[m] = pk2(s1f[2 * m], s1f[2 * m + 1]);
    }
  };

  auto doPV = [&](int cur) {
    __builtin_amdgcn_s_setprio(1);
#pragma unroll
    for (int s = 0; s < 4; ++s) {
      const unsigned int* w = (s < 2) ? w0 : w1;
      const int lo4 = (s & 1) * 4;
      unsigned int x0 = __shfl_xor(w[lo4 + 2], 32, 64);
      unsigned int x1 = __shfl_xor(w[lo4 + 3], 32, 64);
      unsigned int y0 = __shfl_xor(w[lo4],     32, 64);
      unsigned int y1 = __shfl_xor(w[lo4 + 1], 32, 64);
      unsigned int fw[4];
      fw[0] = hh ? x0 : w[lo4];
      fw[1] = hh ? x1 : w[lo4 + 1];
      fw[2] = hh ? w[lo4 + 2] : y0;
      fw[3] = hh ? w[lo4 + 3] : y1;
      short8 pb = *(const short8*)fw;
#pragma unroll
      for (int dt = 0; dt < 4; ++dt) {
        int d = dt * 32 + l31;
        int byte = d * 128 + s * 32 + hh * 16;
        byte ^= (((d & 7) ^ ((d >> 3) & 7)) << 4);
        short8 vf = *(const short8*)((const char*)&Vt[cur][0] + byte);
        Oc[dt] = MFMA32(vf, pb, Oc[dt]);
      }
    }
    __builtin_amdgcn_s_setprio(0);
  };

  const int nt = (kvlen + 63) >> 6;
  short8 vp[2][2];

  issueK(qkv, h, 0, kvlen, woff, tid, &Kl[0][0]);
  if (nt > 1) issueK(qkv, h, 1, kvlen, woff, tid, &Kl[1][0]);
  loadV(qkv, h, 0, kvlen, woff, tid, vp);
  writeV(tid, vp, &Vt[0][0]);
  __syncthreads();

  f32x16 sp0, sp1;
  computeQK(0, 0, &sp0, &sp1);
  __syncthreads();

  for (int t = 0; t < nt - 1; ++t) {
    const int cur = t & 1;
    if (t + 2 < nt) issueK(qkv, h, t + 2, kvlen, woff, tid, &Kl[cur][0]);
    loadV(qkv, h, t + 1, kvlen, woff, tid, vp);

    f32x16 sc0, sc1;
    computeQK(t + 1, cur ^ 1, &sc0, &sc1);
    finishTile(sp0, sp1);
    writeV(tid, vp, &Vt[cur ^ 1][0]);
    doPV(cur);
    __syncthreads();
    sp0 = sc0; sp1 = sc1;
  }
  finishTile(sp0, sp1);
  doPV((nt - 1) & 1);

  const int qg = q0 + wave * 32 + l31;
  if (qg < chunk_end) {
    const float inv = 1.f / l_run;
    unsigned short* op = ob + (long)qg * 1536 + h * 128;
#pragma unroll
    for (int dt = 0; dt < 4; ++dt) {
#pragma unroll
      for (int gblk = 0; gblk < 4; ++gblk) {
        int d = dt * 32 + gblk * 8 + hh * 4;
        unsigned int u0 = pk2(Oc[dt][4 * gblk]     * inv, Oc[dt][4 * gblk + 1] * inv);
        unsigned int u1 = pk2(Oc[dt][4 * gblk + 2] * inv, Oc[dt][4 * gblk + 3] * inv);
        u32x2 uu; uu[0] = u0; uu[1] = u1;
        *(u32x2*)(op + d) = uu;
      }
    }
  }
}

// ---------------- launch ----------------
extern "C" void kernel_launch(void* const* d_in, const int* in_sizes, int n_in,
                              void* d_out, int out_size, void* d_ws, size_t ws_size,
                              hipStream_t stream)
{
  const float* x  = (const float*)d_in[0];
  const float* Wq = (const float*)d_in[1];
  const float* bq = (const float*)d_in[2];
  const float* Wk = (const float*)d_in[3];
  const float* bk = (const float*)d_in[4];
  const float* Wv = (const float*)d_in[5];
  const float* bv = (const float*)d_in[6];
  const float* Wo = (const float*)d_in[7];
  const float* bo = (const float*)d_in[8];
  const float* gq = (const float*)d_in[9];
  const float* gk = (const float*)d_in[10];
  const float* fc = (const float*)d_in[11];
  const float* fs = (const float*)d_in[12];

  char* ws = (char*)d_ws;
  unsigned short* xb   = (unsigned short*)(ws);               // 7168x1536 bf16
  unsigned short* obuf = xb;                                  // aliased after gemm0
  unsigned short* wcat = (unsigned short*)(ws + 22020096);
  unsigned short* wob  = (unsigned short*)(ws + 36175872);
  float*          bcat = (float*)(ws + 40894464);
  unsigned short* qkv  = (unsigned short*)(ws + 40912896);

  cvt_f32_bf16<<<2048, 256, 0, stream>>>(x, xb, 10813440 / 4);
  cvt4_f32_bf16<<<dim3(576, 4), 256, 0, stream>>>(
      Wq, Wk, Wv, Wo,
      wcat, wcat + 2359296, wcat + 4718592, wob, 2359296 / 4);
  hipMemcpyAsync(bcat,        bq, 1536 * 4, hipMemcpyDeviceToDevice, stream);
  hipMemcpyAsync(bcat + 1536, bk, 1536 * 4, hipMemcpyDeviceToDevice, stream);
  hipMemcpyAsync(bcat + 3072, bv, 1536 * 4, hipMemcpyDeviceToDevice, stream);

  gemm8<<<504, 512, 0, stream>>>(xb, wcat, bcat, qkv);

  const float qsc = (float)(1.4426950408889634 / sqrt(128.0));
  normrope2<<<7040, 256, 0, stream>>>(qkv, gq, gk, fc, fs, qsc);

  attn_kern<<<dim3(14, 4, 12), 256, 0, stream>>>(qkv, obuf);

  gemm_bt<<<660, 256, 0, stream>>>(obuf, wob, bo, (float*)d_out, 1536, 1536,
                                   12, 660 / 8, 660 % 8);
}